// Round 7
// baseline (204.088 us; speedup 1.0000x reference)
//
#include <hip/hip_runtime.h>
#include <hip/hip_bf16.h>
#include <math.h>

#define B_  4
#define T_  1024
#define C_  1024
#define H_  16
#define D_  64
#define NEG (-1e30f)
#define LMW 1280   // padded LM row: [0,128)=NEG prefix, [128+rel]=log2-mask

typedef __attribute__((ext_vector_type(8))) __bf16 bf16x8;
typedef __attribute__((ext_vector_type(4))) __bf16 bf16x4;
typedef __attribute__((ext_vector_type(4))) float f32x4;

#define MFMA16(a,b,c) __builtin_amdgcn_mfma_f32_16x16x32_bf16(a,b,c,0,0,0)

__device__ __forceinline__ bf16x8 cvt8(float4 a, float4 b){
  bf16x8 v;
  v[0]=(__bf16)a.x; v[1]=(__bf16)a.y; v[2]=(__bf16)a.z; v[3]=(__bf16)a.w;
  v[4]=(__bf16)b.x; v[5]=(__bf16)b.y; v[6]=(__bf16)b.z; v[7]=(__bf16)b.w;
  return v;
}

__device__ __forceinline__ bf16x4 cvt4(f32x4 a){
  bf16x4 v;
  v[0]=(__bf16)a[0]; v[1]=(__bf16)a[1]; v[2]=(__bf16)a[2]; v[3]=(__bf16)a[3];
  return v;
}

__device__ __forceinline__ void gll16(const __bf16* g, __bf16* l) {
  __builtin_amdgcn_global_load_lds(
      (const __attribute__((address_space(1))) void*)g,
      (__attribute__((address_space(3))) void*)l, 16, 0, 0);
}

// ---------------------------------------------------------------------------
// Fused prep: x cvt | weight transpose+cvt | LM2 table (padded, NEG prefix)
// ---------------------------------------------------------------------------
__global__ __launch_bounds__(256) void prep_kernel(
    const float* __restrict__ x, const float* __restrict__ Wqkv,
    const float* __restrict__ Wproj, const float* __restrict__ sp,
    const float* __restrict__ pw, const float* __restrict__ rw,
    __bf16* __restrict__ x_bf, __bf16* __restrict__ wqkv_t,
    __bf16* __restrict__ wp_t, float* __restrict__ LMp,
    float* __restrict__ loss_out)
{
  __shared__ __bf16 tile[64][72];
  const int id = blockIdx.x, t = threadIdx.x;

  if (id < 2048) {                       // ---- x convert ----
    size_t i = ((size_t)id*256 + t) * 8;
    float4 a = *(const float4*)(x + i);
    float4 b = *(const float4*)(x + i + 4);
    *(bf16x8*)(x_bf + i) = cvt8(a, b);
  } else if (id < 3072) {                // ---- weight transpose+cvt ----
    const float* in; __bf16* outp; int N, bx, by;
    if (id < 2816) { in = Wqkv;  outp = wqkv_t; N = 3*C_; int q2 = id-2048; bx = q2 % 48; by = q2 / 48; }
    else           { in = Wproj; outp = wp_t;   N = C_;   int q2 = id-2816; bx = q2 % 16; by = q2 / 16; }
    const int K = C_, n0 = bx*64, k0 = by*64;
    const int r = t >> 4, c4 = (t & 15) * 4;
    #pragma unroll
    for (int rr = 0; rr < 64; rr += 16) {
      float4 v = *(const float4*)&in[(size_t)(k0 + r + rr)*N + n0 + c4];
      tile[r+rr][c4+0] = (__bf16)v.x; tile[r+rr][c4+1] = (__bf16)v.y;
      tile[r+rr][c4+2] = (__bf16)v.z; tile[r+rr][c4+3] = (__bf16)v.w;
    }
    __syncthreads();
    #pragma unroll
    for (int rr = 0; rr < 64; rr += 16) {
      bf16x4 ov;
      ov[0] = tile[c4+0][r+rr]; ov[1] = tile[c4+1][r+rr];
      ov[2] = tile[c4+2][r+rr]; ov[3] = tile[c4+3][r+rr];
      *(bf16x4*)&outp[(size_t)(n0 + r + rr)*K + k0 + c4] = ov;
    }
  } else {                               // ---- LM2 table + loss ----
    const int h = id - 3072;
    const float PI = 3.14159265358979323846f;
    float s      = 1024.f / (1.f + expf(-sp[h]));
    float period = 2.f + 62.f / (1.f + expf(-pw[h]));
    float ratio  = -0.25f + 0.5f / (1.f + expf(-rw[h]));
    float amp    = 0.25f * period;
    float offset = period * ratio;
    float c1 = 16.f/(PI*PI), c3 = c1/9.f, c5 = c1/25.f;
    if (t < 128) LMp[h*LMW + t] = NEG;   // causal prefix
    #pragma unroll
    for (int i = 0; i < 4; ++i) {
      int rel = t + i*256;
      float ms = fminf(fmaxf((32.f - (float)rel + s) / 32.f, 0.f), 1.f);
      float ph = fmodf(2.f*PI*(float)rel/period, 2.f*PI);
      float wv = c1*cosf(ph) + c3*cosf(3.f*ph) + c5*cosf(5.f*ph);
      wv = wv*amp*0.5f + 0.5f + offset;
      wv = fminf(fmaxf(wv, 0.f), 1.f);
      float v;
      if (fminf(ms, wv) <= 1e-6f) v = NEG;
      else v = log2f(fmaxf(ms,1e-6f)) + log2f(fmaxf(wv,1e-6f));
      LMp[h*LMW + 128 + rel] = v;
    }
    if (h == 0 && t == 0) {
      float acc = 0.f;
      for (int hh = 0; hh < H_; ++hh) {
        float s2      = 1024.f / (1.f + expf(-sp[hh]));
        float period2 = 2.f + 62.f / (1.f + expf(-pw[hh]));
        float ratio2  = -0.25f + 0.5f / (1.f + expf(-rw[hh]));
        float amp2    = 0.25f * period2;
        float off2    = period2 * ratio2;
        float base = 1.f/period2 + 2.f*ratio2 + 0.5f;
        float lt = base < 1.f ? base : 1.f + (0.5f + off2 - amp2);
        acc += (s2 + 32.f) * lt;
      }
      *loss_out = 1e-4f * acc / (float)H_;
    }
  }
}

// ---------------------------------------------------------------------------
// 128xTN bf16 MFMA GEMM (m97 structure) with per-tile operand-swap:
//  - swapped (q/k tiles, proj): acc[ch][tok] = MFMA(W_frag, x_frag) -> C rows
//    are CHANNELS, so each lane holds 4 consecutive channels at one token ->
//    direct bf16x4 / f32x4 stores, NO repack, no extra barriers.
//  - unswapped (v tiles): C rows are tokens -> chunked [d][tok] b64 stores.
// MODE 0: q,k -> [B,H,T,D]; v -> [B,H][kt][64][128].  MODE 1: fp32 out.
// ---------------------------------------------------------------------------
template<int MODE, int TN>
__global__ __launch_bounds__(256) void gemm_bt(
    const __bf16* __restrict__ A, const __bf16* __restrict__ Bt,
    int M, int N, int K,
    __bf16* __restrict__ q_bf, __bf16* __restrict__ k_bf,
    __bf16* __restrict__ vt_bf, float* __restrict__ outf)
{
  __shared__ __align__(16) __bf16 As[128*32];
  __shared__ __align__(16) __bf16 Bs[TN*32];
  constexpr int NI = TN/32;

  const int t = threadIdx.x;
  const int m0 = blockIdx.y * 128, n0 = blockIdx.x * TN;
  const int lane = t & 63, w = t >> 6, quad = lane >> 4, lr = lane & 15;
  const int wm = (w >> 1) * 64, wn = (w & 1) * (TN/2);
  const int srow = t >> 2, scol = (t & 3) * 8;

  const __bf16* gA = A  + (size_t)(m0 + srow)*K + scol;
  const __bf16* gB = Bt + (size_t)(n0 + (TN==128 ? srow : (srow & 63)))*K + scol;
  __bf16* lA0 = As + w*512;
  __bf16* lA1 = As + 64*32 + w*512;
  __bf16* lB0 = Bs + w*512;
  __bf16* lB1 = Bs + 64*32 + w*512;

  // swapped for q/k tiles and proj; unswapped for v tiles (block-uniform)
  const bool sw = (MODE == 1) || (n0 < 2048);

  f32x4 acc[MODE==1 ? NI : 4][4];
  const f32x4 fz = {0.f, 0.f, 0.f, 0.f};
  #pragma unroll
  for (int i = 0; i < (MODE==1 ? NI : 4); ++i)
    #pragma unroll
    for (int j = 0; j < 4; ++j) acc[i][j] = fz;

  const int nk = K >> 5;
  for (int kt = 0; kt < nk; ++kt) {
    __syncthreads();
    gll16(gA + kt*32,                lA0);
    gll16(gA + (size_t)64*K + kt*32, lA1);
    if constexpr (TN == 128) {
      gll16(gB + kt*32,                lB0);
      gll16(gB + (size_t)64*K + kt*32, lB1);
    } else {
      if (srow < 64) gll16(gB + kt*32, lB0);
    }
    __syncthreads();
    bf16x8 af[4], bfr[NI];
    #pragma unroll
    for (int mi = 0; mi < 4; ++mi)
      af[mi] = *(const bf16x8*)&As[(wm + mi*16 + lr)*32 + quad*8];
    #pragma unroll
    for (int ni = 0; ni < NI; ++ni)
      bfr[ni] = *(const bf16x8*)&Bs[(wn + ni*16 + lr)*32 + quad*8];
    if (sw) {
      #pragma unroll
      for (int ci = 0; ci < NI; ++ci)
        #pragma unroll
        for (int ti = 0; ti < 4; ++ti)
          acc[ci][ti] = MFMA16(bfr[ci], af[ti], acc[ci][ti]);
    } else {
      #pragma unroll
      for (int ti = 0; ti < 4; ++ti)
        #pragma unroll
        for (int ci = 0; ci < NI; ++ci)
          acc[ti][ci] = MFMA16(af[ti], bfr[ci], acc[ti][ci]);
    }
  }

  if constexpr (MODE == 0) {
    const int part = n0 >> 10;           // block-uniform
    const int b    = m0 >> 10;
    if (part == 2) {                     // ---- V (unswapped): chunked b64 ----
      #pragma unroll
      for (int mi = 0; mi < 4; ++mi) {
        int tl = (m0 & 1023) + wm + mi*16 + quad*4;
        #pragma unroll
        for (int ni = 0; ni < 4; ++ni) {
          int c = (n0 & 1023) + wn + ni*16 + lr, h = c >> 6, d = c & 63;
          *(bf16x4*)&vt_bf[(size_t)(b*H_ + h)*65536 + (tl>>7)*8192 + d*128 + (tl&127)]
              = cvt4(acc[mi][ni]);
        }
      }
    } else {                             // ---- Q/K (swapped): direct b64 ----
      __bf16* dst = (part == 0) ? q_bf : k_bf;
      #pragma unroll
      for (int ci = 0; ci < 4; ++ci) {
        int c0 = (n0 & 1023) + wn + ci*16 + quad*4;
        int h = c0 >> 6, d0 = c0 & 63;
        __bf16* dbase = dst + (size_t)(b*H_ + h)*(T_*D_) + d0;
        #pragma unroll
        for (int ti = 0; ti < 4; ++ti) {
          int tl = (m0 & 1023) + wm + ti*16 + lr;
          *(bf16x4*)&dbase[(size_t)tl*D_] = cvt4(acc[ci][ti]);
        }
      }
    }
  } else {                               // ---- proj (swapped): f32x4 b128 ----
    #pragma unroll
    for (int ci = 0; ci < NI; ++ci) {
      int cg = n0 + wn + ci*16 + quad*4;
      #pragma unroll
      for (int ti = 0; ti < 4; ++ti) {
        int tok = m0 + wm + ti*16 + lr;
        *(f32x4*)&outf[(size_t)tok*N + cg] = acc[ci][ti];
      }
    }
  }
}

// ---------------------------------------------------------------------------
// Flash attention (unchanged from R6): 512-thread blocks (8 waves, 128 q),
// 512 blocks all co-resident at 2/CU, long+short q-tiles paired per CU.
// K/V via global_load_lds x16; S^T QK; exp2 fixed-base softmax; per-wave
// P round-trip [16][72] in two 64-key halves.
// ---------------------------------------------------------------------------
__global__ __launch_bounds__(512, 4) void attn_kernel(
    const __bf16* __restrict__ q_bf, const __bf16* __restrict__ k_bf,
    const __bf16* __restrict__ vt_bf, const float* __restrict__ LMp,
    const float* __restrict__ sp, __bf16* __restrict__ yatt)
{
  __shared__ __align__(16) __bf16 Klds[2*128*32];   // 16 KB
  __shared__ __align__(16) __bf16 Vlds[4*64*32];    // 16 KB
  __shared__ __align__(16) __bf16 Plds[8*16*72];    // 18 KB

  const int id = blockIdx.x;
  const int g = id & 255, slot = id >> 8;
  const int bh = g & 63, group = g >> 6;            // 0..3
  const int qb = slot ? (3 - group) : (4 + group);  // pair long+short per CU
  const int b = bh >> 4, h = bh & 15;
  const int q0b = qb * 128;
  const int t = threadIdx.x, w = t >> 6, lane = t & 63, quad = lane >> 4, lr = lane & 15;
  const int q0w = q0b + w*16;

  const __bf16* Q  = q_bf  + (size_t)bh * (T_*D_);
  const __bf16* Kg = k_bf  + (size_t)bh * (T_*D_);
  const __bf16* Vg = vt_bf + (size_t)bh * 65536;
  const float* lmp = LMp + h*LMW;

  int offK[2], offV[2];
  #pragma unroll
  for (int j = 0; j < 2; ++j) {
    int c = j*512 + t;
    int half = c >> 9, remr = (c & 511) >> 2, col8 = (c & 3) * 8;
    offK[j] = remr*64 + half*32 + col8;             // LDS [2][128][32]
    int quarter = c >> 8, d = (c & 255) >> 2;
    offV[j] = d*128 + quarter*32 + col8;            // global chunk [64][128]
  }
  __bf16* ldK = Klds + w*512;
  __bf16* ldV = Vlds + w*512;
  __bf16* pw_ = Plds + w*(16*72);

  bf16x8 bq0 = *(const bf16x8*)&Q[(q0w + lr)*D_ + quad*8];
  bf16x8 bq1 = *(const bf16x8*)&Q[(q0w + lr)*D_ + 32 + quad*8];

  const f32x4 fz = {0.f,0.f,0.f,0.f};
  f32x4 o[4]; float l = 0.f;
  #pragma unroll
  for (int i = 0; i < 4; ++i) o[i] = fz;

  float s_h = 1024.f / (1.f + __expf(-sp[h]));
  int kmin = (int)floorf((float)q0b - 33.0f - s_h) + 1;
  int kt0 = kmin > 0 ? (kmin >> 7) : 0;
  const int ktlast = (q0b + 127) >> 7;
  const float s2 = 0.18033688011112042f;            // log2(e)/8

  for (int kt = kt0; kt <= ktlast; ++kt) {
    const int kb = kt << 7;
    __syncthreads();
    #pragma unroll
    for (int j = 0; j < 2; ++j) {
      gll16(Kg + kb*D_ + offK[j], ldK + j*4096);
      gll16(Vg + kt*8192 + offV[j], ldV + j*4096);
    }
    __syncthreads();

    // ---- S^T = K·Q^T from LDS ----
    f32x4 sacc[8];
    #pragma unroll
    for (int ni = 0; ni < 8; ++ni) {
      bf16x8 ak0 = *(const bf16x8*)&Klds[(ni*16 + lr)*32 + quad*8];
      bf16x8 ak1 = *(const bf16x8*)&Klds[4096 + (ni*16 + lr)*32 + quad*8];
      sacc[ni] = MFMA16(ak0, bq0, fz);
      sacc[ni] = MFMA16(ak1, bq1, sacc[ni]);
    }
    // ---- exp2 + PV in two 64-key halves through the per-wave P buffer ----
    #pragma unroll
    for (int hh = 0; hh < 2; ++hh) {
      #pragma unroll
      for (int ni4 = 0; ni4 < 4; ++ni4) {
        int ni = hh*4 + ni4;
        int base = q0w + lr + 128 - kb - ni*16 - quad*4;  // idx = base - r >= 1
        bf16x4 pk;
        #pragma unroll
        for (int r = 0; r < 4; ++r) {
          float tt = fmaf(sacc[ni][r], s2, lmp[base - r]);
          float p;
          asm("v_exp_f32 %0, %1" : "=v"(p) : "v"(tt));    // 2^tt; dead -> 0
          l += p;
          pk[r] = (__bf16)p;
        }
        *(bf16x4*)&pw_[lr*72 + ni4*16 + quad*4] = pk;
      }
      asm volatile("s_waitcnt lgkmcnt(0)" ::: "memory");  // own-wave P visible
      bf16x8 ap0 = *(const bf16x8*)&pw_[lr*72 + quad*8];
      bf16x8 ap1 = *(const bf16x8*)&pw_[lr*72 + 32 + quad*8];
      #pragma unroll
      for (int nj = 0; nj < 4; ++nj) {
        bf16x8 bv0 = *(const bf16x8*)&Vlds[(hh*2+0)*2048 + (nj*16 + lr)*32 + quad*8];
        o[nj] = MFMA16(ap0, bv0, o[nj]);
        bf16x8 bv1 = *(const bf16x8*)&Vlds[(hh*2+1)*2048 + (nj*16 + lr)*32 + quad*8];
        o[nj] = MFMA16(ap1, bv1, o[nj]);
      }
      asm volatile("s_waitcnt lgkmcnt(0)" ::: "memory");  // P reads done before reuse
    }
  }

  // l at (q=lr) per lane: reduce quad partials, then per-row reciprocal
  l += __shfl_xor(l, 16, 64);
  l += __shfl_xor(l, 32, 64);
  float rlq[4];
  #pragma unroll
  for (int r = 0; r < 4; ++r) rlq[r] = 1.f / __shfl(l, quad*4 + r, 64);

  #pragma unroll
  for (int nj = 0; nj < 4; ++nj)
    #pragma unroll
    for (int r = 0; r < 4; ++r) {
      int qg = q0w + quad*4 + r;
      yatt[((size_t)(b*T_ + qg))*C_ + h*D_ + nj*16 + lr] =
          (__bf16)(o[nj][r] * rlq[r]);
    }
}

// ---------------------------------------------------------------------------
extern "C" void kernel_launch(void* const* d_in, const int* in_sizes, int n_in,
                              void* d_out, int out_size, void* d_ws, size_t ws_size,
                              hipStream_t stream) {
  const float* x     = (const float*)d_in[0];
  const float* Wqkv  = (const float*)d_in[1];
  const float* Wproj = (const float*)d_in[2];
  const float* sp    = (const float*)d_in[3];
  const float* pw    = (const float*)d_in[4];
  const float* rw    = (const float*)d_in[5];
  float* out = (float*)d_out;

  char* ws = (char*)d_ws;
  size_t off = 0;
  auto alloc = [&](size_t bytes) -> void* {
    void* p = ws + off;
    off += (bytes + 255) & ~(size_t)255;
    return p;
  };
  float*  LMp    = (float*) alloc((size_t)H_*LMW*4);
  __bf16* wqkv_t = (__bf16*)alloc((size_t)3*C_*C_*2);
  __bf16* wp_t   = (__bf16*)alloc((size_t)C_*C_*2);
  __bf16* q_bf   = (__bf16*)alloc((size_t)B_*H_*T_*D_*2);
  __bf16* k_bf   = (__bf16*)alloc((size_t)B_*H_*T_*D_*2);
  __bf16* vt_bf  = (__bf16*)alloc((size_t)B_*H_*T_*D_*2);
  __bf16* yatt   = (__bf16*)alloc((size_t)B_*T_*C_*2);
  __bf16* x_bf   = yatt;   // aliased: x_bf dead before attn writes yatt

  prep_kernel<<<3088, 256, 0, stream>>>(x, Wqkv, Wproj, sp, pw, rw,
                                        x_bf, wqkv_t, wp_t, LMp,
                                        out + (out_size - 1));
  gemm_bt<0,128><<<dim3(3*C_/128, (B_*T_)/128), 256, 0, stream>>>(
      x_bf, wqkv_t, B_*T_, 3*C_, C_, q_bf, k_bf, vt_bf, nullptr);
  attn_kernel<<<512, 512, 0, stream>>>(q_bf, k_bf, vt_bf, LMp, sp, yatt);
  gemm_bt<1,64><<<dim3(C_/64, (B_*T_)/128), 256, 0, stream>>>(
      yatt, wp_t, B_*T_, C_, C_, nullptr, nullptr, nullptr, out);
}

// Round 8
// 174.556 us; speedup vs baseline: 1.1692x; 1.1692x over previous
//
#include <hip/hip_runtime.h>
#include <hip/hip_bf16.h>
#include <math.h>

#define B_  4
#define T_  1024
#define C_  1024
#define H_  16
#define D_  64
#define NEG (-1e30f)
#define LMW 1280   // padded LM row: [0,128)=NEG prefix, [128+rel]=log2-mask

typedef __attribute__((ext_vector_type(8))) __bf16 bf16x8;
typedef __attribute__((ext_vector_type(4))) __bf16 bf16x4;
typedef __attribute__((ext_vector_type(4))) float f32x4;

#define MFMA16(a,b,c) __builtin_amdgcn_mfma_f32_16x16x32_bf16(a,b,c,0,0,0)

__device__ __forceinline__ bf16x8 cvt8(float4 a, float4 b){
  bf16x8 v;
  v[0]=(__bf16)a.x; v[1]=(__bf16)a.y; v[2]=(__bf16)a.z; v[3]=(__bf16)a.w;
  v[4]=(__bf16)b.x; v[5]=(__bf16)b.y; v[6]=(__bf16)b.z; v[7]=(__bf16)b.w;
  return v;
}

__device__ __forceinline__ void gll16(const __bf16* g, __bf16* l) {
  __builtin_amdgcn_global_load_lds(
      (const __attribute__((address_space(1))) void*)g,
      (__attribute__((address_space(3))) void*)l, 16, 0, 0);
}

// ---------------------------------------------------------------------------
// Fused prep: x cvt | weight transpose+cvt | LM2 table (padded, NEG prefix)
// ---------------------------------------------------------------------------
__global__ __launch_bounds__(256) void prep_kernel(
    const float* __restrict__ x, const float* __restrict__ Wqkv,
    const float* __restrict__ Wproj, const float* __restrict__ sp,
    const float* __restrict__ pw, const float* __restrict__ rw,
    __bf16* __restrict__ x_bf, __bf16* __restrict__ wqkv_t,
    __bf16* __restrict__ wp_t, float* __restrict__ LMp,
    float* __restrict__ loss_out)
{
  __shared__ __bf16 tile[64][72];
  const int id = blockIdx.x, t = threadIdx.x;

  if (id < 2048) {                       // ---- x convert ----
    size_t i = ((size_t)id*256 + t) * 8;
    float4 a = *(const float4*)(x + i);
    float4 b = *(const float4*)(x + i + 4);
    *(bf16x8*)(x_bf + i) = cvt8(a, b);
  } else if (id < 3072) {                // ---- weight transpose+cvt ----
    const float* in; __bf16* outp; int N, bx, by;
    if (id < 2816) { in = Wqkv;  outp = wqkv_t; N = 3*C_; int q2 = id-2048; bx = q2 % 48; by = q2 / 48; }
    else           { in = Wproj; outp = wp_t;   N = C_;   int q2 = id-2816; bx = q2 % 16; by = q2 / 16; }
    const int K = C_, n0 = bx*64, k0 = by*64;
    const int r = t >> 4, c4 = (t & 15) * 4;
    #pragma unroll
    for (int rr = 0; rr < 64; rr += 16) {
      float4 v = *(const float4*)&in[(size_t)(k0 + r + rr)*N + n0 + c4];
      tile[r+rr][c4+0] = (__bf16)v.x; tile[r+rr][c4+1] = (__bf16)v.y;
      tile[r+rr][c4+2] = (__bf16)v.z; tile[r+rr][c4+3] = (__bf16)v.w;
    }
    __syncthreads();
    #pragma unroll
    for (int rr = 0; rr < 64; rr += 16) {
      bf16x4 ov;
      ov[0] = tile[c4+0][r+rr]; ov[1] = tile[c4+1][r+rr];
      ov[2] = tile[c4+2][r+rr]; ov[3] = tile[c4+3][r+rr];
      *(bf16x4*)&outp[(size_t)(n0 + r + rr)*K + k0 + c4] = ov;
    }
  } else {                               // ---- LM2 table + loss ----
    const int h = id - 3072;
    const float PI = 3.14159265358979323846f;
    float s      = 1024.f / (1.f + expf(-sp[h]));
    float period = 2.f + 62.f / (1.f + expf(-pw[h]));
    float ratio  = -0.25f + 0.5f / (1.f + expf(-rw[h]));
    float amp    = 0.25f * period;
    float offset = period * ratio;
    float c1 = 16.f/(PI*PI), c3 = c1/9.f, c5 = c1/25.f;
    if (t < 128) LMp[h*LMW + t] = NEG;   // causal prefix
    #pragma unroll
    for (int i = 0; i < 4; ++i) {
      int rel = t + i*256;
      float ms = fminf(fmaxf((32.f - (float)rel + s) / 32.f, 0.f), 1.f);
      float ph = fmodf(2.f*PI*(float)rel/period, 2.f*PI);
      float wv = c1*cosf(ph) + c3*cosf(3.f*ph) + c5*cosf(5.f*ph);
      wv = wv*amp*0.5f + 0.5f + offset;
      wv = fminf(fmaxf(wv, 0.f), 1.f);
      float v;
      if (fminf(ms, wv) <= 1e-6f) v = NEG;
      else v = log2f(fmaxf(ms,1e-6f)) + log2f(fmaxf(wv,1e-6f));
      LMp[h*LMW + 128 + rel] = v;
    }
    if (h == 0 && t == 0) {
      float acc = 0.f;
      for (int hh = 0; hh < H_; ++hh) {
        float s2      = 1024.f / (1.f + expf(-sp[hh]));
        float period2 = 2.f + 62.f / (1.f + expf(-pw[hh]));
        float ratio2  = -0.25f + 0.5f / (1.f + expf(-rw[hh]));
        float amp2    = 0.25f * period2;
        float off2    = period2 * ratio2;
        float base = 1.f/period2 + 2.f*ratio2 + 0.5f;
        float lt = base < 1.f ? base : 1.f + (0.5f + off2 - amp2);
        acc += (s2 + 32.f) * lt;
      }
      *loss_out = 1e-4f * acc / (float)H_;
    }
  }
}

// ---------------------------------------------------------------------------
// 128xTN bf16 MFMA GEMM (m97 structure) with XOR bank swizzle:
// staging lane loads global 16B-chunk (t&3)^((srow>>1)&3) (same 64B segment,
// coalescing unchanged); fragment reads use quad^((lr>>1)&3) -> ds_read_b128
// lands 2 lanes/bank (free) instead of 8-way conflicted.
// MODE 0: q,k via LDS-repack (stride 132) -> coalesced 16B stores;
//         v -> k-tile-chunked [B,H][kt][64][128].  MODE 1: fp32 [M][N].
// ---------------------------------------------------------------------------
template<int MODE, int TN>
__global__ __launch_bounds__(256) void gemm_bt(
    const __bf16* __restrict__ A, const __bf16* __restrict__ Bt,
    int M, int N, int K,
    __bf16* __restrict__ q_bf, __bf16* __restrict__ k_bf,
    __bf16* __restrict__ vt_bf, float* __restrict__ outf)
{
  __shared__ __align__(16) __bf16 smem[128*132];   // 33KB pool
  __bf16* As = smem;                                // 128*32
  __bf16* Bs = smem + 128*32;                       // TN*32
  constexpr int NI = TN/32;

  const int t = threadIdx.x;
  const int m0 = blockIdx.y * 128, n0 = blockIdx.x * TN;
  const int lane = t & 63, w = t >> 6, quad = lane >> 4, lr = lane & 15;
  const int wm = (w >> 1) * 64, wn = (w & 1) * (TN/2);
  const int srow = t >> 2;
  const int scol = ((t & 3) ^ ((srow >> 1) & 3)) * 8;   // swizzled source chunk
  const int quadx = quad ^ ((lr >> 1) & 3);             // swizzled read chunk

  const __bf16* gA = A  + (size_t)(m0 + srow)*K + scol;
  const __bf16* gB = Bt + (size_t)(n0 + (TN==128 ? srow : (srow & 63)))*K + scol;
  __bf16* lA0 = As + w*512;
  __bf16* lA1 = As + 64*32 + w*512;
  __bf16* lB0 = Bs + w*512;
  __bf16* lB1 = Bs + 64*32 + w*512;

  f32x4 acc[4][NI];
  const f32x4 fz = {0.f, 0.f, 0.f, 0.f};
  #pragma unroll
  for (int mi = 0; mi < 4; ++mi)
    #pragma unroll
    for (int ni = 0; ni < NI; ++ni) acc[mi][ni] = fz;

  const int nk = K >> 5;
  for (int kt = 0; kt < nk; ++kt) {
    __syncthreads();
    gll16(gA + kt*32,                lA0);
    gll16(gA + (size_t)64*K + kt*32, lA1);
    if constexpr (TN == 128) {
      gll16(gB + kt*32,                lB0);
      gll16(gB + (size_t)64*K + kt*32, lB1);
    } else {
      if (srow < 64) gll16(gB + kt*32, lB0);
    }
    __syncthreads();
    bf16x8 af[4], bfr[NI];
    #pragma unroll
    for (int mi = 0; mi < 4; ++mi)
      af[mi] = *(const bf16x8*)&As[(wm + mi*16 + lr)*32 + quadx*8];
    #pragma unroll
    for (int ni = 0; ni < NI; ++ni)
      bfr[ni] = *(const bf16x8*)&Bs[(wn + ni*16 + lr)*32 + quadx*8];
    #pragma unroll
    for (int mi = 0; mi < 4; ++mi)
      #pragma unroll
      for (int ni = 0; ni < NI; ++ni)
        acc[mi][ni] = MFMA16(af[mi], bfr[ni], acc[mi][ni]);
  }

  if constexpr (MODE == 0) {
    const int part = n0 >> 10;           // block-uniform
    const int b    = m0 >> 10;
    if (part == 2) {                     // ---- V: chunked 8B stores ----
      #pragma unroll
      for (int mi = 0; mi < 4; ++mi) {
        int tl = (m0 & 1023) + wm + mi*16 + quad*4;
        #pragma unroll
        for (int ni = 0; ni < NI; ++ni) {
          int c = (n0 & 1023) + wn + ni*16 + lr, h = c >> 6, d = c & 63;
          bf16x4 pk;
          pk[0] = (__bf16)acc[mi][ni][0]; pk[1] = (__bf16)acc[mi][ni][1];
          pk[2] = (__bf16)acc[mi][ni][2]; pk[3] = (__bf16)acc[mi][ni][3];
          *(bf16x4*)&vt_bf[(size_t)(b*H_ + h)*65536 + (tl>>7)*8192 + d*128 + (tl&127)] = pk;
        }
      }
    } else {                             // ---- Q/K: LDS repack, stride 132 ----
      __syncthreads();
      #pragma unroll
      for (int mi = 0; mi < 4; ++mi)
        #pragma unroll
        for (int ni = 0; ni < NI; ++ni)
          #pragma unroll
          for (int r = 0; r < 4; ++r)
            smem[(wm + mi*16 + quad*4 + r)*132 + wn + ni*16 + lr] =
                (__bf16)acc[mi][ni][r];
      __syncthreads();
      __bf16* dst = (part == 0) ? q_bf : k_bf;
      const int mrow = t >> 4, col8 = (t & 15) * 8;
      const int c0 = (n0 & 1023) + col8, h = c0 >> 6, d = c0 & 63;
      __bf16* dbase = dst + (size_t)(b*H_ + h)*(T_*D_) + d;
      #pragma unroll
      for (int rr = 0; rr < 8; ++rr) {
        int m = mrow + rr*16;
        int tl = (m0 & 1023) + m;
        *(bf16x8*)&dbase[(size_t)tl*D_] = *(const bf16x8*)&smem[m*132 + col8];
      }
    }
  } else {
    #pragma unroll
    for (int mi = 0; mi < 4; ++mi) {
      int mg = m0 + wm + mi*16 + quad*4;
      #pragma unroll
      for (int r = 0; r < 4; ++r) {
        float* orow = outf + (size_t)(mg + r)*N + n0 + wn;
        #pragma unroll
        for (int ni = 0; ni < NI; ++ni)
          orow[ni*16 + lr] = acc[mi][ni][r];
      }
    }
  }
}

// ---------------------------------------------------------------------------
// Flash attention (R6 structure + XOR bank swizzle on K/V tiles):
// 512-thread blocks (8 waves, 128 q), 512 blocks all co-resident at 2/CU,
// long+short q-tiles paired per CU. K/V via global_load_lds x16 with
// swizzled source chunks; S^T QK; exp2 fixed-base softmax; per-wave
// P round-trip [16][72] in two 64-key halves.
// ---------------------------------------------------------------------------
__global__ __launch_bounds__(512, 4) void attn_kernel(
    const __bf16* __restrict__ q_bf, const __bf16* __restrict__ k_bf,
    const __bf16* __restrict__ vt_bf, const float* __restrict__ LMp,
    const float* __restrict__ sp, __bf16* __restrict__ yatt)
{
  __shared__ __align__(16) __bf16 Klds[2*128*32];   // 16 KB
  __shared__ __align__(16) __bf16 Vlds[4*64*32];    // 16 KB
  __shared__ __align__(16) __bf16 Plds[8*16*72];    // 18 KB

  const int id = blockIdx.x;
  const int g = id & 255, slot = id >> 8;
  const int bh = g & 63, group = g >> 6;            // 0..3
  const int qb = slot ? (3 - group) : (4 + group);  // pair long+short per CU
  const int b = bh >> 4, h = bh & 15;
  const int q0b = qb * 128;
  const int t = threadIdx.x, w = t >> 6, lane = t & 63, quad = lane >> 4, lr = lane & 15;
  const int q0w = q0b + w*16;
  const int quadx = quad ^ ((lr >> 1) & 3);         // swizzled read chunk

  const __bf16* Q  = q_bf  + (size_t)bh * (T_*D_);
  const __bf16* Kg = k_bf  + (size_t)bh * (T_*D_);
  const __bf16* Vg = vt_bf + (size_t)bh * 65536;
  const float* lmp = LMp + h*LMW;

  int offK[2], offV[2];
  #pragma unroll
  for (int j = 0; j < 2; ++j) {
    int c = j*512 + t;
    int half = c >> 9, remr = (c & 511) >> 2;
    int ck = ((c & 3) ^ ((remr >> 1) & 3)) * 8;     // swizzled source chunk
    offK[j] = remr*64 + half*32 + ck;               // LDS [2][128][32]
    int quarter = c >> 8, d = (c & 255) >> 2;
    int cv = ((c & 3) ^ ((d >> 1) & 3)) * 8;
    offV[j] = d*128 + quarter*32 + cv;              // global chunk [64][128]
  }
  __bf16* ldK = Klds + w*512;
  __bf16* ldV = Vlds + w*512;
  __bf16* pw_ = Plds + w*(16*72);

  bf16x8 bq0 = *(const bf16x8*)&Q[(q0w + lr)*D_ + quad*8];
  bf16x8 bq1 = *(const bf16x8*)&Q[(q0w + lr)*D_ + 32 + quad*8];

  const f32x4 fz = {0.f,0.f,0.f,0.f};
  f32x4 o[4]; float l = 0.f;
  #pragma unroll
  for (int i = 0; i < 4; ++i) o[i] = fz;

  float s_h = 1024.f / (1.f + __expf(-sp[h]));
  int kmin = (int)floorf((float)q0b - 33.0f - s_h) + 1;
  int kt0 = kmin > 0 ? (kmin >> 7) : 0;
  const int ktlast = (q0b + 127) >> 7;
  const float s2 = 0.18033688011112042f;            // log2(e)/8

  for (int kt = kt0; kt <= ktlast; ++kt) {
    const int kb = kt << 7;
    __syncthreads();
    #pragma unroll
    for (int j = 0; j < 2; ++j) {
      gll16(Kg + kb*D_ + offK[j], ldK + j*4096);
      gll16(Vg + kt*8192 + offV[j], ldV + j*4096);
    }
    __syncthreads();

    // ---- S^T = K·Q^T from LDS ----
    f32x4 sacc[8];
    #pragma unroll
    for (int ni = 0; ni < 8; ++ni) {
      bf16x8 ak0 = *(const bf16x8*)&Klds[(ni*16 + lr)*32 + quadx*8];
      bf16x8 ak1 = *(const bf16x8*)&Klds[4096 + (ni*16 + lr)*32 + quadx*8];
      sacc[ni] = MFMA16(ak0, bq0, fz);
      sacc[ni] = MFMA16(ak1, bq1, sacc[ni]);
    }
    // ---- exp2 + PV in two 64-key halves through the per-wave P buffer ----
    #pragma unroll
    for (int hh = 0; hh < 2; ++hh) {
      #pragma unroll
      for (int ni4 = 0; ni4 < 4; ++ni4) {
        int ni = hh*4 + ni4;
        int base = q0w + lr + 128 - kb - ni*16 - quad*4;  // idx = base - r >= 1
        bf16x4 pk;
        #pragma unroll
        for (int r = 0; r < 4; ++r) {
          float tt = fmaf(sacc[ni][r], s2, lmp[base - r]);
          float p;
          asm("v_exp_f32 %0, %1" : "=v"(p) : "v"(tt));    // 2^tt; dead -> 0
          l += p;
          pk[r] = (__bf16)p;
        }
        *(bf16x4*)&pw_[lr*72 + ni4*16 + quad*4] = pk;
      }
      asm volatile("s_waitcnt lgkmcnt(0)" ::: "memory");  // own-wave P visible
      bf16x8 ap0 = *(const bf16x8*)&pw_[lr*72 + quad*8];
      bf16x8 ap1 = *(const bf16x8*)&pw_[lr*72 + 32 + quad*8];
      #pragma unroll
      for (int nj = 0; nj < 4; ++nj) {
        bf16x8 bv0 = *(const bf16x8*)&Vlds[(hh*2+0)*2048 + (nj*16 + lr)*32 + quadx*8];
        o[nj] = MFMA16(ap0, bv0, o[nj]);
        bf16x8 bv1 = *(const bf16x8*)&Vlds[(hh*2+1)*2048 + (nj*16 + lr)*32 + quadx*8];
        o[nj] = MFMA16(ap1, bv1, o[nj]);
      }
      asm volatile("s_waitcnt lgkmcnt(0)" ::: "memory");  // P reads done before reuse
    }
  }

  // l at (q=lr) per lane: reduce quad partials, then per-row reciprocal
  l += __shfl_xor(l, 16, 64);
  l += __shfl_xor(l, 32, 64);
  float rlq[4];
  #pragma unroll
  for (int r = 0; r < 4; ++r) rlq[r] = 1.f / __shfl(l, quad*4 + r, 64);

  #pragma unroll
  for (int nj = 0; nj < 4; ++nj)
    #pragma unroll
    for (int r = 0; r < 4; ++r) {
      int qg = q0w + quad*4 + r;
      yatt[((size_t)(b*T_ + qg))*C_ + h*D_ + nj*16 + lr] =
          (__bf16)(o[nj][r] * rlq[r]);
    }
}

// ---------------------------------------------------------------------------
extern "C" void kernel_launch(void* const* d_in, const int* in_sizes, int n_in,
                              void* d_out, int out_size, void* d_ws, size_t ws_size,
                              hipStream_t stream) {
  const float* x     = (const float*)d_in[0];
  const float* Wqkv  = (const float*)d_in[1];
  const float* Wproj = (const float*)d_in[2];
  const float* sp    = (const float*)d_in[3];
  const float* pw    = (const float*)d_in[4];
  const float* rw    = (const float*)d_in[5];
  float* out = (float*)d_out;

  char* ws = (char*)d_ws;
  size_t off = 0;
  auto alloc = [&](size_t bytes) -> void* {
    void* p = ws + off;
    off += (bytes + 255) & ~(size_t)255;
    return p;
  };
  float*  LMp    = (float*) alloc((size_t)H_*LMW*4);
  __bf16* wqkv_t = (__bf16*)alloc((size_t)3*C_*C_*2);
  __bf16* wp_t   = (__bf16*)alloc((size_t)C_*C_*2);
  __bf16* q_bf   = (__bf16*)alloc((size_t)B_*H_*T_*D_*2);
  __bf16* k_bf   = (__bf16*)alloc((size_t)B_*H_*T_*D_*2);
  __bf16* vt_bf  = (__bf16*)alloc((size_t)B_*H_*T_*D_*2);
  __bf16* yatt   = (__bf16*)alloc((size_t)B_*T_*C_*2);
  __bf16* x_bf   = yatt;   // aliased: x_bf dead before attn writes yatt

  prep_kernel<<<3088, 256, 0, stream>>>(x, Wqkv, Wproj, sp, pw, rw,
                                        x_bf, wqkv_t, wp_t, LMp,
                                        out + (out_size - 1));
  gemm_bt<0,128><<<dim3(3*C_/128, (B_*T_)/128), 256, 0, stream>>>(
      x_bf, wqkv_t, B_*T_, 3*C_, C_, q_bf, k_bf, vt_bf, nullptr);
  attn_kernel<<<512, 512, 0, stream>>>(q_bf, k_bf, vt_bf, LMp, sp, yatt);
  gemm_bt<1,64><<<dim3(C_/64, (B_*T_)/128), 256, 0, stream>>>(
      yatt, wp_t, B_*T_, C_, C_, nullptr, nullptr, nullptr, out);
}

// Round 9
// 166.346 us; speedup vs baseline: 1.2269x; 1.0494x over previous
//
#include <hip/hip_runtime.h>
#include <hip/hip_bf16.h>
#include <math.h>

#define B_  4
#define T_  1024
#define C_  1024
#define H_  16
#define D_  64
#define NEG (-1e30f)
#define LMW 1280   // padded LM row: [0,128)=NEG prefix, [128+rel]=log2-mask

typedef __attribute__((ext_vector_type(8))) __bf16 bf16x8;
typedef __attribute__((ext_vector_type(4))) __bf16 bf16x4;
typedef __attribute__((ext_vector_type(4))) float f32x4;

#define MFMA16(a,b,c) __builtin_amdgcn_mfma_f32_16x16x32_bf16(a,b,c,0,0,0)

__device__ __forceinline__ bf16x8 cvt8(float4 a, float4 b){
  bf16x8 v;
  v[0]=(__bf16)a.x; v[1]=(__bf16)a.y; v[2]=(__bf16)a.z; v[3]=(__bf16)a.w;
  v[4]=(__bf16)b.x; v[5]=(__bf16)b.y; v[6]=(__bf16)b.z; v[7]=(__bf16)b.w;
  return v;
}

__device__ __forceinline__ void gll16(const __bf16* g, __bf16* l) {
  __builtin_amdgcn_global_load_lds(
      (const __attribute__((address_space(1))) void*)g,
      (__attribute__((address_space(3))) void*)l, 16, 0, 0);
}

// ---------------------------------------------------------------------------
// Fused prep: x cvt | weight transpose+cvt | LM2 table (padded, NEG prefix)
// ---------------------------------------------------------------------------
__global__ __launch_bounds__(256) void prep_kernel(
    const float* __restrict__ x, const float* __restrict__ Wqkv,
    const float* __restrict__ Wproj, const float* __restrict__ sp,
    const float* __restrict__ pw, const float* __restrict__ rw,
    __bf16* __restrict__ x_bf, __bf16* __restrict__ wqkv_t,
    __bf16* __restrict__ wp_t, float* __restrict__ LMp,
    float* __restrict__ loss_out)
{
  __shared__ __bf16 tile[64][72];
  const int id = blockIdx.x, t = threadIdx.x;

  if (id < 2048) {                       // ---- x convert ----
    size_t i = ((size_t)id*256 + t) * 8;
    float4 a = *(const float4*)(x + i);
    float4 b = *(const float4*)(x + i + 4);
    *(bf16x8*)(x_bf + i) = cvt8(a, b);
  } else if (id < 3072) {                // ---- weight transpose+cvt ----
    const float* in; __bf16* outp; int N, bx, by;
    if (id < 2816) { in = Wqkv;  outp = wqkv_t; N = 3*C_; int q2 = id-2048; bx = q2 % 48; by = q2 / 48; }
    else           { in = Wproj; outp = wp_t;   N = C_;   int q2 = id-2816; bx = q2 % 16; by = q2 / 16; }
    const int K = C_, n0 = bx*64, k0 = by*64;
    const int r = t >> 4, c4 = (t & 15) * 4;
    #pragma unroll
    for (int rr = 0; rr < 64; rr += 16) {
      float4 v = *(const float4*)&in[(size_t)(k0 + r + rr)*N + n0 + c4];
      tile[r+rr][c4+0] = (__bf16)v.x; tile[r+rr][c4+1] = (__bf16)v.y;
      tile[r+rr][c4+2] = (__bf16)v.z; tile[r+rr][c4+3] = (__bf16)v.w;
    }
    __syncthreads();
    #pragma unroll
    for (int rr = 0; rr < 64; rr += 16) {
      bf16x4 ov;
      ov[0] = tile[c4+0][r+rr]; ov[1] = tile[c4+1][r+rr];
      ov[2] = tile[c4+2][r+rr]; ov[3] = tile[c4+3][r+rr];
      *(bf16x4*)&outp[(size_t)(n0 + r + rr)*K + k0 + c4] = ov;
    }
  } else {                               // ---- LM2 table + loss ----
    const int h = id - 3072;
    const float PI = 3.14159265358979323846f;
    float s      = 1024.f / (1.f + expf(-sp[h]));
    float period = 2.f + 62.f / (1.f + expf(-pw[h]));
    float ratio  = -0.25f + 0.5f / (1.f + expf(-rw[h]));
    float amp    = 0.25f * period;
    float offset = period * ratio;
    float c1 = 16.f/(PI*PI), c3 = c1/9.f, c5 = c1/25.f;
    if (t < 128) LMp[h*LMW + t] = NEG;   // causal prefix
    #pragma unroll
    for (int i = 0; i < 4; ++i) {
      int rel = t + i*256;
      float ms = fminf(fmaxf((32.f - (float)rel + s) / 32.f, 0.f), 1.f);
      float ph = fmodf(2.f*PI*(float)rel/period, 2.f*PI);
      float wv = c1*cosf(ph) + c3*cosf(3.f*ph) + c5*cosf(5.f*ph);
      wv = wv*amp*0.5f + 0.5f + offset;
      wv = fminf(fmaxf(wv, 0.f), 1.f);
      float v;
      if (fminf(ms, wv) <= 1e-6f) v = NEG;
      else v = log2f(fmaxf(ms,1e-6f)) + log2f(fmaxf(wv,1e-6f));
      LMp[h*LMW + 128 + rel] = v;
    }
    if (h == 0 && t == 0) {
      float acc = 0.f;
      for (int hh = 0; hh < H_; ++hh) {
        float s2      = 1024.f / (1.f + expf(-sp[hh]));
        float period2 = 2.f + 62.f / (1.f + expf(-pw[hh]));
        float ratio2  = -0.25f + 0.5f / (1.f + expf(-rw[hh]));
        float amp2    = 0.25f * period2;
        float off2    = period2 * ratio2;
        float base = 1.f/period2 + 2.f*ratio2 + 0.5f;
        float lt = base < 1.f ? base : 1.f + (0.5f + off2 - amp2);
        acc += (s2 + 32.f) * lt;
      }
      *loss_out = 1e-4f * acc / (float)H_;
    }
  }
}

// ---------------------------------------------------------------------------
// 128xTN bf16 MFMA GEMM (m97 structure) + XOR bank swizzle + XCD swizzle.
// 1D grid: xcd=id&7 gets 4 m-stripes x all n -> A-rows L2-resident per XCD.
// MODE 0: q,k via LDS-repack (stride 132) -> coalesced 16B stores;
//         v -> k-tile-chunked [B,H][kt][64][128].  MODE 1: fp32 [M][N].
// ---------------------------------------------------------------------------
template<int MODE, int TN>
__global__ __launch_bounds__(256) void gemm_bt(
    const __bf16* __restrict__ A, const __bf16* __restrict__ Bt,
    int M, int N, int K,
    __bf16* __restrict__ q_bf, __bf16* __restrict__ k_bf,
    __bf16* __restrict__ vt_bf, float* __restrict__ outf)
{
  __shared__ __align__(16) __bf16 smem[128*132];   // 33KB pool
  __bf16* As = smem;                                // 128*32
  __bf16* Bs = smem + 128*32;                       // TN*32
  constexpr int NI = TN/32;

  const int t = threadIdx.x;
  const int id = blockIdx.x;
  const int xcd = id & 7, s = id >> 3;              // XCD-aware decode
  const int m0 = (xcd*4 + (s & 3)) * 128;           // M/128 == 32 stripes
  const int n0 = (s >> 2) * TN;
  const int lane = t & 63, w = t >> 6, quad = lane >> 4, lr = lane & 15;
  const int wm = (w >> 1) * 64, wn = (w & 1) * (TN/2);
  const int srow = t >> 2;
  const int scol = ((t & 3) ^ ((srow >> 1) & 3)) * 8;   // swizzled source chunk
  const int quadx = quad ^ ((lr >> 1) & 3);             // swizzled read chunk

  const __bf16* gA = A  + (size_t)(m0 + srow)*K + scol;
  const __bf16* gB = Bt + (size_t)(n0 + (TN==128 ? srow : (srow & 63)))*K + scol;
  __bf16* lA0 = As + w*512;
  __bf16* lA1 = As + 64*32 + w*512;
  __bf16* lB0 = Bs + w*512;
  __bf16* lB1 = Bs + 64*32 + w*512;

  f32x4 acc[4][NI];
  const f32x4 fz = {0.f, 0.f, 0.f, 0.f};
  #pragma unroll
  for (int mi = 0; mi < 4; ++mi)
    #pragma unroll
    for (int ni = 0; ni < NI; ++ni) acc[mi][ni] = fz;

  const int nk = K >> 5;
  for (int kt = 0; kt < nk; ++kt) {
    __syncthreads();
    gll16(gA + kt*32,                lA0);
    gll16(gA + (size_t)64*K + kt*32, lA1);
    if constexpr (TN == 128) {
      gll16(gB + kt*32,                lB0);
      gll16(gB + (size_t)64*K + kt*32, lB1);
    } else {
      if (srow < 64) gll16(gB + kt*32, lB0);
    }
    __syncthreads();
    bf16x8 af[4], bfr[NI];
    #pragma unroll
    for (int mi = 0; mi < 4; ++mi)
      af[mi] = *(const bf16x8*)&As[(wm + mi*16 + lr)*32 + quadx*8];
    #pragma unroll
    for (int ni = 0; ni < NI; ++ni)
      bfr[ni] = *(const bf16x8*)&Bs[(wn + ni*16 + lr)*32 + quadx*8];
    #pragma unroll
    for (int mi = 0; mi < 4; ++mi)
      #pragma unroll
      for (int ni = 0; ni < NI; ++ni)
        acc[mi][ni] = MFMA16(af[mi], bfr[ni], acc[mi][ni]);
  }

  if constexpr (MODE == 0) {
    const int part = n0 >> 10;           // block-uniform
    const int b    = m0 >> 10;
    if (part == 2) {                     // ---- V: chunked 8B stores ----
      #pragma unroll
      for (int mi = 0; mi < 4; ++mi) {
        int tl = (m0 & 1023) + wm + mi*16 + quad*4;
        #pragma unroll
        for (int ni = 0; ni < NI; ++ni) {
          int c = (n0 & 1023) + wn + ni*16 + lr, h = c >> 6, d = c & 63;
          bf16x4 pk;
          pk[0] = (__bf16)acc[mi][ni][0]; pk[1] = (__bf16)acc[mi][ni][1];
          pk[2] = (__bf16)acc[mi][ni][2]; pk[3] = (__bf16)acc[mi][ni][3];
          *(bf16x4*)&vt_bf[(size_t)(b*H_ + h)*65536 + (tl>>7)*8192 + d*128 + (tl&127)] = pk;
        }
      }
    } else {                             // ---- Q/K: LDS repack, stride 132 ----
      __syncthreads();
      #pragma unroll
      for (int mi = 0; mi < 4; ++mi)
        #pragma unroll
        for (int ni = 0; ni < NI; ++ni)
          #pragma unroll
          for (int r = 0; r < 4; ++r)
            smem[(wm + mi*16 + quad*4 + r)*132 + wn + ni*16 + lr] =
                (__bf16)acc[mi][ni][r];
      __syncthreads();
      __bf16* dst = (part == 0) ? q_bf : k_bf;
      const int mrow = t >> 4, col8 = (t & 15) * 8;
      const int c0 = (n0 & 1023) + col8, h = c0 >> 6, d = c0 & 63;
      __bf16* dbase = dst + (size_t)(b*H_ + h)*(T_*D_) + d;
      #pragma unroll
      for (int rr = 0; rr < 8; ++rr) {
        int m = mrow + rr*16;
        int tl = (m0 & 1023) + m;
        *(bf16x8*)&dbase[(size_t)tl*D_] = *(const bf16x8*)&smem[m*132 + col8];
      }
    }
  } else {
    #pragma unroll
    for (int mi = 0; mi < 4; ++mi) {
      int mg = m0 + wm + mi*16 + quad*4;
      #pragma unroll
      for (int r = 0; r < 4; ++r) {
        float* orow = outf + (size_t)(mg + r)*N + n0 + wn;
        #pragma unroll
        for (int ni = 0; ni < NI; ++ni)
          orow[ni*16 + lr] = acc[mi][ni][r];
      }
    }
  }
}

// ---------------------------------------------------------------------------
// Flash attention (R8 structure + ones-MFMA l):
// 512-thread blocks (8 waves, 128 q), 512 blocks all co-resident at 2/CU,
// long+short q-tiles paired per CU. K/V via global_load_lds x16 with XOR
// swizzle; S^T QK; exp2 fixed-base softmax; per-wave P round-trip [16][72]
// in two 64-key halves. l is computed by an extra MFMA with a ones
// B-operand: D[q][*] = sum_k P[q][k], landing l(q=quad*4+r) directly in
// the register the epilogue divides by — no VALU adds, no shuffles.
// ---------------------------------------------------------------------------
__global__ __launch_bounds__(512, 4) void attn_kernel(
    const __bf16* __restrict__ q_bf, const __bf16* __restrict__ k_bf,
    const __bf16* __restrict__ vt_bf, const float* __restrict__ LMp,
    const float* __restrict__ sp, __bf16* __restrict__ yatt)
{
  __shared__ __align__(16) __bf16 Klds[2*128*32];   // 16 KB
  __shared__ __align__(16) __bf16 Vlds[4*64*32];    // 16 KB
  __shared__ __align__(16) __bf16 Plds[8*16*72];    // 18 KB

  const int id = blockIdx.x;
  const int g = id & 255, slot = id >> 8;
  const int bh = g & 63, group = g >> 6;            // 0..3
  const int qb = slot ? (3 - group) : (4 + group);  // pair long+short per CU
  const int b = bh >> 4, h = bh & 15;
  const int q0b = qb * 128;
  const int t = threadIdx.x, w = t >> 6, lane = t & 63, quad = lane >> 4, lr = lane & 15;
  const int q0w = q0b + w*16;
  const int quadx = quad ^ ((lr >> 1) & 3);         // swizzled read chunk

  const __bf16* Q  = q_bf  + (size_t)bh * (T_*D_);
  const __bf16* Kg = k_bf  + (size_t)bh * (T_*D_);
  const __bf16* Vg = vt_bf + (size_t)bh * 65536;
  const float* lmp = LMp + h*LMW;

  int offK[2], offV[2];
  #pragma unroll
  for (int j = 0; j < 2; ++j) {
    int c = j*512 + t;
    int half = c >> 9, remr = (c & 511) >> 2;
    int ck = ((c & 3) ^ ((remr >> 1) & 3)) * 8;     // swizzled source chunk
    offK[j] = remr*64 + half*32 + ck;               // LDS [2][128][32]
    int quarter = c >> 8, d = (c & 255) >> 2;
    int cv = ((c & 3) ^ ((d >> 1) & 3)) * 8;
    offV[j] = d*128 + quarter*32 + cv;              // global chunk [64][128]
  }
  __bf16* ldK = Klds + w*512;
  __bf16* ldV = Vlds + w*512;
  __bf16* pw_ = Plds + w*(16*72);

  bf16x8 bq0 = *(const bf16x8*)&Q[(q0w + lr)*D_ + quad*8];
  bf16x8 bq1 = *(const bf16x8*)&Q[(q0w + lr)*D_ + 32 + quad*8];

  bf16x8 ones;
  #pragma unroll
  for (int i = 0; i < 8; ++i) ones[i] = (__bf16)1.0f;

  const f32x4 fz = {0.f,0.f,0.f,0.f};
  f32x4 o[4], o4;
  #pragma unroll
  for (int i = 0; i < 4; ++i) o[i] = fz;
  o4 = fz;

  float s_h = 1024.f / (1.f + __expf(-sp[h]));
  int kmin = (int)floorf((float)q0b - 33.0f - s_h) + 1;
  int kt0 = kmin > 0 ? (kmin >> 7) : 0;
  const int ktlast = (q0b + 127) >> 7;
  const float s2 = 0.18033688011112042f;            // log2(e)/8

  for (int kt = kt0; kt <= ktlast; ++kt) {
    const int kb = kt << 7;
    __syncthreads();
    #pragma unroll
    for (int j = 0; j < 2; ++j) {
      gll16(Kg + kb*D_ + offK[j], ldK + j*4096);
      gll16(Vg + kt*8192 + offV[j], ldV + j*4096);
    }
    __syncthreads();

    // ---- S^T = K·Q^T from LDS ----
    f32x4 sacc[8];
    #pragma unroll
    for (int ni = 0; ni < 8; ++ni) {
      bf16x8 ak0 = *(const bf16x8*)&Klds[(ni*16 + lr)*32 + quadx*8];
      bf16x8 ak1 = *(const bf16x8*)&Klds[4096 + (ni*16 + lr)*32 + quadx*8];
      sacc[ni] = MFMA16(ak0, bq0, fz);
      sacc[ni] = MFMA16(ak1, bq1, sacc[ni]);
    }
    // ---- exp2 + PV in two 64-key halves through the per-wave P buffer ----
    #pragma unroll
    for (int hh = 0; hh < 2; ++hh) {
      #pragma unroll
      for (int ni4 = 0; ni4 < 4; ++ni4) {
        int ni = hh*4 + ni4;
        int base = q0w + lr + 128 - kb - ni*16 - quad*4;  // idx = base - r >= 1
        bf16x4 pk;
        #pragma unroll
        for (int r = 0; r < 4; ++r) {
          float tt = fmaf(sacc[ni][r], s2, lmp[base - r]);
          float p;
          asm("v_exp_f32 %0, %1" : "=v"(p) : "v"(tt));    // 2^tt; dead -> 0
          pk[r] = (__bf16)p;
        }
        *(bf16x4*)&pw_[lr*72 + ni4*16 + quad*4] = pk;
      }
      asm volatile("s_waitcnt lgkmcnt(0)" ::: "memory");  // own-wave P visible
      bf16x8 ap0 = *(const bf16x8*)&pw_[lr*72 + quad*8];
      bf16x8 ap1 = *(const bf16x8*)&pw_[lr*72 + 32 + quad*8];
      o4 = MFMA16(ap0, ones, o4);                         // l(q) accumulation
      o4 = MFMA16(ap1, ones, o4);
      #pragma unroll
      for (int nj = 0; nj < 4; ++nj) {
        bf16x8 bv0 = *(const bf16x8*)&Vlds[(hh*2+0)*2048 + (nj*16 + lr)*32 + quadx*8];
        o[nj] = MFMA16(ap0, bv0, o[nj]);
        bf16x8 bv1 = *(const bf16x8*)&Vlds[(hh*2+1)*2048 + (nj*16 + lr)*32 + quadx*8];
        o[nj] = MFMA16(ap1, bv1, o[nj]);
      }
      asm volatile("s_waitcnt lgkmcnt(0)" ::: "memory");  // P reads done before reuse
    }
  }

  // o4[r] = l(q = q0w + quad*4 + r) — exactly the rows this lane stores
  float rlq[4];
  #pragma unroll
  for (int r = 0; r < 4; ++r) rlq[r] = 1.f / o4[r];

  #pragma unroll
  for (int nj = 0; nj < 4; ++nj)
    #pragma unroll
    for (int r = 0; r < 4; ++r) {
      int qg = q0w + quad*4 + r;
      yatt[((size_t)(b*T_ + qg))*C_ + h*D_ + nj*16 + lr] =
          (__bf16)(o[nj][r] * rlq[r]);
    }
}

// ---------------------------------------------------------------------------
extern "C" void kernel_launch(void* const* d_in, const int* in_sizes, int n_in,
                              void* d_out, int out_size, void* d_ws, size_t ws_size,
                              hipStream_t stream) {
  const float* x     = (const float*)d_in[0];
  const float* Wqkv  = (const float*)d_in[1];
  const float* Wproj = (const float*)d_in[2];
  const float* sp    = (const float*)d_in[3];
  const float* pw    = (const float*)d_in[4];
  const float* rw    = (const float*)d_in[5];
  float* out = (float*)d_out;

  char* ws = (char*)d_ws;
  size_t off = 0;
  auto alloc = [&](size_t bytes) -> void* {
    void* p = ws + off;
    off += (bytes + 255) & ~(size_t)255;
    return p;
  };
  float*  LMp    = (float*) alloc((size_t)H_*LMW*4);
  __bf16* wqkv_t = (__bf16*)alloc((size_t)3*C_*C_*2);
  __bf16* wp_t   = (__bf16*)alloc((size_t)C_*C_*2);
  __bf16* q_bf   = (__bf16*)alloc((size_t)B_*H_*T_*D_*2);
  __bf16* k_bf   = (__bf16*)alloc((size_t)B_*H_*T_*D_*2);
  __bf16* vt_bf  = (__bf16*)alloc((size_t)B_*H_*T_*D_*2);
  __bf16* yatt   = (__bf16*)alloc((size_t)B_*T_*C_*2);
  __bf16* x_bf   = yatt;   // aliased: x_bf dead before attn writes yatt

  prep_kernel<<<3088, 256, 0, stream>>>(x, Wqkv, Wproj, sp, pw, rw,
                                        x_bf, wqkv_t, wp_t, LMp,
                                        out + (out_size - 1));
  gemm_bt<0,128><<<768, 256, 0, stream>>>(
      x_bf, wqkv_t, B_*T_, 3*C_, C_, q_bf, k_bf, vt_bf, nullptr);
  attn_kernel<<<512, 512, 0, stream>>>(q_bf, k_bf, vt_bf, LMp, sp, yatt);
  gemm_bt<1,64><<<512, 256, 0, stream>>>(
      yatt, wp_t, B_*T_, C_, C_, nullptr, nullptr, nullptr, out);
}

// Round 10
// 159.321 us; speedup vs baseline: 1.2810x; 1.0441x over previous
//
#include <hip/hip_runtime.h>
#include <hip/hip_bf16.h>
#include <math.h>

#define B_  4
#define T_  1024
#define C_  1024
#define H_  16
#define D_  64
#define NEG (-1e30f)
#define LMW 1280   // padded LM row: [0,128)=NEG prefix, [128+rel]=log2-mask

typedef __attribute__((ext_vector_type(8))) __bf16 bf16x8;
typedef __attribute__((ext_vector_type(4))) __bf16 bf16x4;
typedef __attribute__((ext_vector_type(4))) float f32x4;

#define MFMA16(a,b,c) __builtin_amdgcn_mfma_f32_16x16x32_bf16(a,b,c,0,0,0)

__device__ __forceinline__ bf16x8 cvt8(float4 a, float4 b){
  bf16x8 v;
  v[0]=(__bf16)a.x; v[1]=(__bf16)a.y; v[2]=(__bf16)a.z; v[3]=(__bf16)a.w;
  v[4]=(__bf16)b.x; v[5]=(__bf16)b.y; v[6]=(__bf16)b.z; v[7]=(__bf16)b.w;
  return v;
}

__device__ __forceinline__ void gll16(const __bf16* g, __bf16* l) {
  __builtin_amdgcn_global_load_lds(
      (const __attribute__((address_space(1))) void*)g,
      (__attribute__((address_space(3))) void*)l, 16, 0, 0);
}

// ---------------------------------------------------------------------------
// Fused prep: x cvt | weight transpose+cvt | LM2 table (padded, NEG prefix)
// ---------------------------------------------------------------------------
__global__ __launch_bounds__(256) void prep_kernel(
    const float* __restrict__ x, const float* __restrict__ Wqkv,
    const float* __restrict__ Wproj, const float* __restrict__ sp,
    const float* __restrict__ pw, const float* __restrict__ rw,
    __bf16* __restrict__ x_bf, __bf16* __restrict__ wqkv_t,
    __bf16* __restrict__ wp_t, float* __restrict__ LMp,
    float* __restrict__ loss_out)
{
  __shared__ __bf16 tile[64][72];
  const int id = blockIdx.x, t = threadIdx.x;

  if (id < 2048) {                       // ---- x convert ----
    size_t i = ((size_t)id*256 + t) * 8;
    float4 a = *(const float4*)(x + i);
    float4 b = *(const float4*)(x + i + 4);
    *(bf16x8*)(x_bf + i) = cvt8(a, b);
  } else if (id < 3072) {                // ---- weight transpose+cvt ----
    const float* in; __bf16* outp; int N, bx, by;
    if (id < 2816) { in = Wqkv;  outp = wqkv_t; N = 3*C_; int q2 = id-2048; bx = q2 % 48; by = q2 / 48; }
    else           { in = Wproj; outp = wp_t;   N = C_;   int q2 = id-2816; bx = q2 % 16; by = q2 / 16; }
    const int K = C_, n0 = bx*64, k0 = by*64;
    const int r = t >> 4, c4 = (t & 15) * 4;
    #pragma unroll
    for (int rr = 0; rr < 64; rr += 16) {
      float4 v = *(const float4*)&in[(size_t)(k0 + r + rr)*N + n0 + c4];
      tile[r+rr][c4+0] = (__bf16)v.x; tile[r+rr][c4+1] = (__bf16)v.y;
      tile[r+rr][c4+2] = (__bf16)v.z; tile[r+rr][c4+3] = (__bf16)v.w;
    }
    __syncthreads();
    #pragma unroll
    for (int rr = 0; rr < 64; rr += 16) {
      bf16x4 ov;
      ov[0] = tile[c4+0][r+rr]; ov[1] = tile[c4+1][r+rr];
      ov[2] = tile[c4+2][r+rr]; ov[3] = tile[c4+3][r+rr];
      *(bf16x4*)&outp[(size_t)(n0 + r + rr)*K + k0 + c4] = ov;
    }
  } else {                               // ---- LM2 table + loss ----
    const int h = id - 3072;
    const float PI = 3.14159265358979323846f;
    float s      = 1024.f / (1.f + expf(-sp[h]));
    float period = 2.f + 62.f / (1.f + expf(-pw[h]));
    float ratio  = -0.25f + 0.5f / (1.f + expf(-rw[h]));
    float amp    = 0.25f * period;
    float offset = period * ratio;
    float c1 = 16.f/(PI*PI), c3 = c1/9.f, c5 = c1/25.f;
    if (t < 128) LMp[h*LMW + t] = NEG;   // causal prefix
    #pragma unroll
    for (int i = 0; i < 4; ++i) {
      int rel = t + i*256;
      float ms = fminf(fmaxf((32.f - (float)rel + s) / 32.f, 0.f), 1.f);
      float ph = fmodf(2.f*PI*(float)rel/period, 2.f*PI);
      float wv = c1*cosf(ph) + c3*cosf(3.f*ph) + c5*cosf(5.f*ph);
      wv = wv*amp*0.5f + 0.5f + offset;
      wv = fminf(fmaxf(wv, 0.f), 1.f);
      float v;
      if (fminf(ms, wv) <= 1e-6f) v = NEG;
      else v = log2f(fmaxf(ms,1e-6f)) + log2f(fmaxf(wv,1e-6f));
      LMp[h*LMW + 128 + rel] = v;
    }
    if (h == 0 && t == 0) {
      float acc = 0.f;
      for (int hh = 0; hh < H_; ++hh) {
        float s2      = 1024.f / (1.f + expf(-sp[hh]));
        float period2 = 2.f + 62.f / (1.f + expf(-pw[hh]));
        float ratio2  = -0.25f + 0.5f / (1.f + expf(-rw[hh]));
        float amp2    = 0.25f * period2;
        float off2    = period2 * ratio2;
        float base = 1.f/period2 + 2.f*ratio2 + 0.5f;
        float lt = base < 1.f ? base : 1.f + (0.5f + off2 - amp2);
        acc += (s2 + 32.f) * lt;
      }
      *loss_out = 1e-4f * acc / (float)H_;
    }
  }
}

// ---------------------------------------------------------------------------
// 128xTN bf16 MFMA GEMM, BK=64: two 32-K half-tiles per barrier pair
// (32 MFMA/wave between barriers; staging 32 KB fits the repack pool so
// occupancy is unchanged — the variable that killed m132's BK=128).
// XOR bank swizzle on staging/reads; XCD swizzle (xcd=id&7, 4 m-stripes).
// MODE 0: q,k via LDS-repack (stride 132) -> coalesced 16B stores;
//         v -> k-tile-chunked [B,H][kt][64][128].  MODE 1: fp32 [M][N].
// ---------------------------------------------------------------------------
template<int MODE, int TN>
__global__ __launch_bounds__(256) void gemm_bt(
    const __bf16* __restrict__ A, const __bf16* __restrict__ Bt,
    int M, int N, int K,
    __bf16* __restrict__ q_bf, __bf16* __restrict__ k_bf,
    __bf16* __restrict__ vt_bf, float* __restrict__ outf)
{
  constexpr int BSH = TN*32;                       // one B half-tile (elems)
  constexpr int PSZ = (MODE==0) ? 128*132 : (8192 + 2*BSH);
  __shared__ __align__(16) __bf16 smem[PSZ];
  __bf16* As = smem;                               // [2 halves][128][32]
  __bf16* Bs = smem + 8192;                        // [2 halves][TN][32]

  const int t = threadIdx.x;
  const int id = blockIdx.x;
  const int xcd = id & 7, s = id >> 3;             // XCD-aware decode
  const int m0 = (xcd*4 + (s & 3)) * 128;          // M/128 == 32 stripes
  const int n0 = (s >> 2) * TN;
  const int lane = t & 63, w = t >> 6, quad = lane >> 4, lr = lane & 15;
  const int wm = (w >> 1) * 64, wn = (w & 1) * (TN/2);
  const int srow = t >> 2;
  const int scol = ((t & 3) ^ ((srow >> 1) & 3)) * 8;   // swizzled source chunk
  const int quadx = quad ^ ((lr >> 1) & 3);             // swizzled read chunk

  const __bf16* gA = A  + (size_t)(m0 + srow)*K + scol;
  const __bf16* gB = Bt + (size_t)(n0 + (TN==128 ? srow : (srow & 63)))*K + scol;
  __bf16* lA00 = As + w*512;              // half0 rows 0-63
  __bf16* lA01 = As + 2048 + w*512;       // half0 rows 64-127
  __bf16* lA10 = As + 4096 + w*512;       // half1 rows 0-63
  __bf16* lA11 = As + 6144 + w*512;       // half1 rows 64-127
  __bf16* lB00 = Bs + w*512;
  __bf16* lB01 = Bs + 2048 + w*512;       // TN=128 only
  __bf16* lB10 = Bs + BSH + w*512;
  __bf16* lB11 = Bs + BSH + 2048 + w*512; // TN=128 only

  constexpr int NI = TN/32;
  f32x4 acc[4][NI];
  const f32x4 fz = {0.f, 0.f, 0.f, 0.f};
  #pragma unroll
  for (int mi = 0; mi < 4; ++mi)
    #pragma unroll
    for (int ni = 0; ni < NI; ++ni) acc[mi][ni] = fz;

  const int nk = K >> 6;                  // BK = 64
  for (int kt = 0; kt < nk; ++kt) {
    __syncthreads();
    gll16(gA + kt*64,                     lA00);
    gll16(gA + (size_t)64*K + kt*64,      lA01);
    gll16(gA + kt*64 + 32,                lA10);
    gll16(gA + (size_t)64*K + kt*64 + 32, lA11);
    if constexpr (TN == 128) {
      gll16(gB + kt*64,                     lB00);
      gll16(gB + (size_t)64*K + kt*64,      lB01);
      gll16(gB + kt*64 + 32,                lB10);
      gll16(gB + (size_t)64*K + kt*64 + 32, lB11);
    } else {
      gll16(gB + kt*64,      lB00);
      gll16(gB + kt*64 + 32, lB10);
    }
    __syncthreads();
    bf16x8 af0[4], af1[4], bf0[NI], bf1[NI];
    #pragma unroll
    for (int mi = 0; mi < 4; ++mi) {
      af0[mi] = *(const bf16x8*)&As[(wm + mi*16 + lr)*32 + quadx*8];
      af1[mi] = *(const bf16x8*)&As[4096 + (wm + mi*16 + lr)*32 + quadx*8];
    }
    #pragma unroll
    for (int ni = 0; ni < NI; ++ni) {
      bf0[ni] = *(const bf16x8*)&Bs[(wn + ni*16 + lr)*32 + quadx*8];
      bf1[ni] = *(const bf16x8*)&Bs[BSH + (wn + ni*16 + lr)*32 + quadx*8];
    }
    #pragma unroll
    for (int mi = 0; mi < 4; ++mi)
      #pragma unroll
      for (int ni = 0; ni < NI; ++ni) {
        acc[mi][ni] = MFMA16(af0[mi], bf0[ni], acc[mi][ni]);
        acc[mi][ni] = MFMA16(af1[mi], bf1[ni], acc[mi][ni]);
      }
  }

  if constexpr (MODE == 0) {
    const int part = n0 >> 10;           // block-uniform
    const int b    = m0 >> 10;
    if (part == 2) {                     // ---- V: chunked 8B stores ----
      #pragma unroll
      for (int mi = 0; mi < 4; ++mi) {
        int tl = (m0 & 1023) + wm + mi*16 + quad*4;
        #pragma unroll
        for (int ni = 0; ni < NI; ++ni) {
          int c = (n0 & 1023) + wn + ni*16 + lr, h = c >> 6, d = c & 63;
          bf16x4 pk;
          pk[0] = (__bf16)acc[mi][ni][0]; pk[1] = (__bf16)acc[mi][ni][1];
          pk[2] = (__bf16)acc[mi][ni][2]; pk[3] = (__bf16)acc[mi][ni][3];
          *(bf16x4*)&vt_bf[(size_t)(b*H_ + h)*65536 + (tl>>7)*8192 + d*128 + (tl&127)] = pk;
        }
      }
    } else {                             // ---- Q/K: LDS repack, stride 132 ----
      __syncthreads();
      #pragma unroll
      for (int mi = 0; mi < 4; ++mi)
        #pragma unroll
        for (int ni = 0; ni < NI; ++ni)
          #pragma unroll
          for (int r = 0; r < 4; ++r)
            smem[(wm + mi*16 + quad*4 + r)*132 + wn + ni*16 + lr] =
                (__bf16)acc[mi][ni][r];
      __syncthreads();
      __bf16* dst = (part == 0) ? q_bf : k_bf;
      const int mrow = t >> 4, col8 = (t & 15) * 8;
      const int c0 = (n0 & 1023) + col8, h = c0 >> 6, d = c0 & 63;
      __bf16* dbase = dst + (size_t)(b*H_ + h)*(T_*D_) + d;
      #pragma unroll
      for (int rr = 0; rr < 8; ++rr) {
        int m = mrow + rr*16;
        int tl = (m0 & 1023) + m;
        *(bf16x8*)&dbase[(size_t)tl*D_] = *(const bf16x8*)&smem[m*132 + col8];
      }
    }
  } else {
    #pragma unroll
    for (int mi = 0; mi < 4; ++mi) {
      int mg = m0 + wm + mi*16 + quad*4;
      #pragma unroll
      for (int r = 0; r < 4; ++r) {
        float* orow = outf + (size_t)(mg + r)*N + n0 + wn;
        #pragma unroll
        for (int ni = 0; ni < NI; ++ni)
          orow[ni*16 + lr] = acc[mi][ni][r];
      }
    }
  }
}

// ---------------------------------------------------------------------------
// Flash attention (R9, frozen): 512-thread blocks (8 waves, 128 q), 512
// blocks co-resident at 2/CU, long+short q-tiles paired per CU. K/V via
// global_load_lds x16 + XOR swizzle; S^T QK; exp2 fixed-base softmax;
// per-wave P round-trip [16][72] in two 64-key halves; l via ones-MFMA.
// ---------------------------------------------------------------------------
__global__ __launch_bounds__(512, 4) void attn_kernel(
    const __bf16* __restrict__ q_bf, const __bf16* __restrict__ k_bf,
    const __bf16* __restrict__ vt_bf, const float* __restrict__ LMp,
    const float* __restrict__ sp, __bf16* __restrict__ yatt)
{
  __shared__ __align__(16) __bf16 Klds[2*128*32];   // 16 KB
  __shared__ __align__(16) __bf16 Vlds[4*64*32];    // 16 KB
  __shared__ __align__(16) __bf16 Plds[8*16*72];    // 18 KB

  const int id = blockIdx.x;
  const int g = id & 255, slot = id >> 8;
  const int bh = g & 63, group = g >> 6;            // 0..3
  const int qb = slot ? (3 - group) : (4 + group);  // pair long+short per CU
  const int b = bh >> 4, h = bh & 15;
  const int q0b = qb * 128;
  const int t = threadIdx.x, w = t >> 6, lane = t & 63, quad = lane >> 4, lr = lane & 15;
  const int q0w = q0b + w*16;
  const int quadx = quad ^ ((lr >> 1) & 3);         // swizzled read chunk

  const __bf16* Q  = q_bf  + (size_t)bh * (T_*D_);
  const __bf16* Kg = k_bf  + (size_t)bh * (T_*D_);
  const __bf16* Vg = vt_bf + (size_t)bh * 65536;
  const float* lmp = LMp + h*LMW;

  int offK[2], offV[2];
  #pragma unroll
  for (int j = 0; j < 2; ++j) {
    int c = j*512 + t;
    int half = c >> 9, remr = (c & 511) >> 2;
    int ck = ((c & 3) ^ ((remr >> 1) & 3)) * 8;     // swizzled source chunk
    offK[j] = remr*64 + half*32 + ck;               // LDS [2][128][32]
    int quarter = c >> 8, d = (c & 255) >> 2;
    int cv = ((c & 3) ^ ((d >> 1) & 3)) * 8;
    offV[j] = d*128 + quarter*32 + cv;              // global chunk [64][128]
  }
  __bf16* ldK = Klds + w*512;
  __bf16* ldV = Vlds + w*512;
  __bf16* pw_ = Plds + w*(16*72);

  bf16x8 bq0 = *(const bf16x8*)&Q[(q0w + lr)*D_ + quad*8];
  bf16x8 bq1 = *(const bf16x8*)&Q[(q0w + lr)*D_ + 32 + quad*8];

  bf16x8 ones;
  #pragma unroll
  for (int i = 0; i < 8; ++i) ones[i] = (__bf16)1.0f;

  const f32x4 fz = {0.f,0.f,0.f,0.f};
  f32x4 o[4], o4;
  #pragma unroll
  for (int i = 0; i < 4; ++i) o[i] = fz;
  o4 = fz;

  float s_h = 1024.f / (1.f + __expf(-sp[h]));
  int kmin = (int)floorf((float)q0b - 33.0f - s_h) + 1;
  int kt0 = kmin > 0 ? (kmin >> 7) : 0;
  const int ktlast = (q0b + 127) >> 7;
  const float s2 = 0.18033688011112042f;            // log2(e)/8

  for (int kt = kt0; kt <= ktlast; ++kt) {
    const int kb = kt << 7;
    __syncthreads();
    #pragma unroll
    for (int j = 0; j < 2; ++j) {
      gll16(Kg + kb*D_ + offK[j], ldK + j*4096);
      gll16(Vg + kt*8192 + offV[j], ldV + j*4096);
    }
    __syncthreads();

    // ---- S^T = K·Q^T from LDS ----
    f32x4 sacc[8];
    #pragma unroll
    for (int ni = 0; ni < 8; ++ni) {
      bf16x8 ak0 = *(const bf16x8*)&Klds[(ni*16 + lr)*32 + quadx*8];
      bf16x8 ak1 = *(const bf16x8*)&Klds[4096 + (ni*16 + lr)*32 + quadx*8];
      sacc[ni] = MFMA16(ak0, bq0, fz);
      sacc[ni] = MFMA16(ak1, bq1, sacc[ni]);
    }
    // ---- exp2 + PV in two 64-key halves through the per-wave P buffer ----
    #pragma unroll
    for (int hh = 0; hh < 2; ++hh) {
      #pragma unroll
      for (int ni4 = 0; ni4 < 4; ++ni4) {
        int ni = hh*4 + ni4;
        int base = q0w + lr + 128 - kb - ni*16 - quad*4;  // idx = base - r >= 1
        bf16x4 pk;
        #pragma unroll
        for (int r = 0; r < 4; ++r) {
          float tt = fmaf(sacc[ni][r], s2, lmp[base - r]);
          float p;
          asm("v_exp_f32 %0, %1" : "=v"(p) : "v"(tt));    // 2^tt; dead -> 0
          pk[r] = (__bf16)p;
        }
        *(bf16x4*)&pw_[lr*72 + ni4*16 + quad*4] = pk;
      }
      asm volatile("s_waitcnt lgkmcnt(0)" ::: "memory");  // own-wave P visible
      bf16x8 ap0 = *(const bf16x8*)&pw_[lr*72 + quad*8];
      bf16x8 ap1 = *(const bf16x8*)&pw_[lr*72 + 32 + quad*8];
      o4 = MFMA16(ap0, ones, o4);                         // l(q) accumulation
      o4 = MFMA16(ap1, ones, o4);
      #pragma unroll
      for (int nj = 0; nj < 4; ++nj) {
        bf16x8 bv0 = *(const bf16x8*)&Vlds[(hh*2+0)*2048 + (nj*16 + lr)*32 + quadx*8];
        o[nj] = MFMA16(ap0, bv0, o[nj]);
        bf16x8 bv1 = *(const bf16x8*)&Vlds[(hh*2+1)*2048 + (nj*16 + lr)*32 + quadx*8];
        o[nj] = MFMA16(ap1, bv1, o[nj]);
      }
      asm volatile("s_waitcnt lgkmcnt(0)" ::: "memory");  // P reads done before reuse
    }
  }

  // o4[r] = l(q = q0w + quad*4 + r) — exactly the rows this lane stores
  float rlq[4];
  #pragma unroll
  for (int r = 0; r < 4; ++r) rlq[r] = 1.f / o4[r];

  #pragma unroll
  for (int nj = 0; nj < 4; ++nj)
    #pragma unroll
    for (int r = 0; r < 4; ++r) {
      int qg = q0w + quad*4 + r;
      yatt[((size_t)(b*T_ + qg))*C_ + h*D_ + nj*16 + lr] =
          (__bf16)(o[nj][r] * rlq[r]);
    }
}

// ---------------------------------------------------------------------------
extern "C" void kernel_launch(void* const* d_in, const int* in_sizes, int n_in,
                              void* d_out, int out_size, void* d_ws, size_t ws_size,
                              hipStream_t stream) {
  const float* x     = (const float*)d_in[0];
  const float* Wqkv  = (const float*)d_in[1];
  const float* Wproj = (const float*)d_in[2];
  const float* sp    = (const float*)d_in[3];
  const float* pw    = (const float*)d_in[4];
  const float* rw    = (const float*)d_in[5];
  float* out = (float*)d_out;

  char* ws = (char*)d_ws;
  size_t off = 0;
  auto alloc = [&](size_t bytes) -> void* {
    void* p = ws + off;
    off += (bytes + 255) & ~(size_t)255;
    return p;
  };
  float*  LMp    = (float*) alloc((size_t)H_*LMW*4);
  __bf16* wqkv_t = (__bf16*)alloc((size_t)3*C_*C_*2);
  __bf16* wp_t   = (__bf16*)alloc((size_t)C_*C_*2);
  __bf16* q_bf   = (__bf16*)alloc((size_t)B_*H_*T_*D_*2);
  __bf16* k_bf   = (__bf16*)alloc((size_t)B_*H_*T_*D_*2);
  __bf16* vt_bf  = (__bf16*)alloc((size_t)B_*H_*T_*D_*2);
  __bf16* yatt   = (__bf16*)alloc((size_t)B_*T_*C_*2);
  __bf16* x_bf   = yatt;   // aliased: x_bf dead before attn writes yatt

  prep_kernel<<<3088, 256, 0, stream>>>(x, Wqkv, Wproj, sp, pw, rw,
                                        x_bf, wqkv_t, wp_t, LMp,
                                        out + (out_size - 1));
  gemm_bt<0,128><<<768, 256, 0, stream>>>(
      x_bf, wqkv_t, B_*T_, 3*C_, C_, q_bf, k_bf, vt_bf, nullptr);
  attn_kernel<<<512, 512, 0, stream>>>(q_bf, k_bf, vt_bf, LMp, sp, yatt);
  gemm_bt<1,64><<<512, 256, 0, stream>>>(
      yatt, wp_t, B_*T_, C_, C_, nullptr, nullptr, nullptr, out);
}